// Round 15
// baseline (10.869 us; speedup 1.0000x reference)
//
#include <hip/hip_runtime.h>

#define DIM    128
#define LAYERS 8
#define NQ     7

// ---- lane-permutation primitives ----
template<int CTRL>
__device__ __forceinline__ float dpp_f(float x) {
    return __int_as_float(__builtin_amdgcn_update_dpp(0, __float_as_int(x), CTRL, 0xF, 0xF, true));
}
__device__ __forceinline__ float swz31(float x) {   // l ^ 31 (within 32-lane half)
    return __int_as_float(__builtin_amdgcn_ds_swizzle(__float_as_int(x), 0x7C1F));
}
// x[l^32] / x[l^16] via CDNA4 permlane self-swap. Self-swap returns the two
// half-duplicates in SOME order; (a+b)-x recovers the partner regardless of
// direction/order (abs err ~4e-7 << 0.068 tolerance). s_nop 1 covers the
// VALU->permlane source wait-state hazard across the asm boundary.
__device__ __forceinline__ float permxor32(float x) {
    float a = x, b = x;
    asm("s_nop 1\n\tv_permlane32_swap_b32 %0, %1" : "+v"(a), "+v"(b));
    return (a + b) - x;
}
__device__ __forceinline__ float permxor16(float x) {
    float a = x, b = x;
    asm("s_nop 1\n\tv_permlane16_swap_b32 %0, %1" : "+v"(a), "+v"(b));
    return (a + b) - x;
}

// XOR-shuffle by compile-time mask M (lane index l -> l^M), cheapest pipe per M.
template<int M>
__device__ __forceinline__ float shfx(float x) {
    if constexpr      (M == 1)  return dpp_f<0xB1>(x);               // quad_perm [1,0,3,2]
    else if constexpr (M == 2)  return dpp_f<0x4E>(x);               // quad_perm [2,3,0,1]
    else if constexpr (M == 3)  return dpp_f<0x1B>(x);               // quad_perm [3,2,1,0]
    else if constexpr (M == 4)  return dpp_f<0x141>(dpp_f<0x1B>(x)); // l^3 then l^7 -> l^4
    else if constexpr (M == 7)  return dpp_f<0x141>(x);              // row_half_mirror
    else if constexpr (M == 8)  return dpp_f<0x128>(x);              // row_ror:8 == l^8
    else if constexpr (M == 15) return dpp_f<0x140>(x);              // row_mirror == l^15
    else if constexpr (M == 16) return permxor16(x);
    else if constexpr (M == 31) return swz31(x);
    else if constexpr (M == 32) return permxor32(x);
    else                        return permxor32(swz31(x));          // M == 63
}

// ---- complex helpers ----
// row G=(g0r,g0i,g1r,g1i): returns g0*c0 + g1*c1 (complex)
__device__ __forceinline__ float2 rowmul(float4 G, float2 c0, float2 c1) {
    float2 r;
    r.x = G.x * c0.x - G.y * c0.y + G.z * c1.x - G.w * c1.y;
    r.y = G.x * c0.y + G.y * c0.x + G.z * c1.y + G.w * c1.x;
    return r;
}
// butterfly: v' = M[rv,rv]*v + M[rv,!rv]*partner ; G is row rv of the gate
__device__ __forceinline__ float2 bfly(float2 v, float2 p, int rv, float4 G) {
    return rv ? rowmul(G, p, v) : rowmul(G, v, p);
}
template<int M>
__device__ __forceinline__ void bstep(float2& lo, float2& hi, int rlo, int rhi,
                                      float4 Glo, float4 Ghi) {
    float2 plo, phl;
    plo.x = shfx<M>(lo.x); plo.y = shfx<M>(lo.y);
    phl.x = shfx<M>(hi.x); phl.y = shfx<M>(hi.y);
    lo = bfly(lo, plo, rlo, Glo);
    hi = bfly(hi, phl, rhi, Ghi);
}

// Entangler fold (verified algebraically, n=2 worked example + telescoping):
// store a[y] = t[pi(y)]; pi alternates id (even layers) / Gi (odd), and is id
// after layer 7 -> no physical gathers, plain final store. Odd-layer gates use
// masks G*e_b = {127,63,31,15,7,3,1} and selects y_b ^ y_{b+1}.
__global__ __launch_bounds__(64) void qsim_kernel(
        const float* __restrict__ state,          // (TB, 128) f32
        const float* __restrict__ params,         // (TB, 8, 7, 3) f32
        float* __restrict__ out,                  // f32 planar: [TB*128 re | TB*128 im]
        int TB) {
    __shared__ float4 gm[LAYERS * NQ][2];

    const int L  = threadIdx.x;
    const int bb = blockIdx.x;

    float2 lo = make_float2(state[bb * DIM + L],      0.0f);
    float2 hi = make_float2(state[bb * DIM + L + 64], 0.0f);

    if (L < LAYERS * NQ) {
        const float* pp = params + (size_t)bb * (LAYERS * NQ * 3) + L * 3;
        const float omega = pp[0], theta = pp[1], phi = pp[2];
        const float a = 0.5f * (phi + omega), b = 0.5f * (phi - omega), t = 0.5f * theta;
        const float sa = __sinf(a), ca = __cosf(a);
        const float sb = __sinf(b), cb = __cosf(b);
        const float st = __sinf(t), ct = __cosf(t);
        gm[L][0] = make_float4(ca * ct, -sa * ct, -cb * st, -sb * st); // row0: m00,m01
        gm[L][1] = make_float4(cb * st, -sb * st,  ca * ct,  sa * ct); // row1: m10,m11
    }
    __syncthreads();

    #pragma unroll
    for (int l = 0; l < LAYERS; ++l) {
        const int base = l * NQ;
        const float4 R0 = gm[base][0];
        const float4 R1 = gm[base][1];
        if ((l & 1) == 0) {
            // ---- even layer: plain basis, masks 64(in-lane),32,16,8,4,2,1 ----
            const int b5 = (L >> 5) & 1, b4 = (L >> 4) & 1, b3 = (L >> 3) & 1;
            const int b2 = (L >> 2) & 1, b1 = (L >> 1) & 1, b0 = L & 1;
            const float4 G1 = gm[base + 1][b5];
            const float4 G2 = gm[base + 2][b4];
            const float4 G3 = gm[base + 3][b3];
            const float4 G4 = gm[base + 4][b2];
            const float4 G5 = gm[base + 5][b1];
            const float4 G6 = gm[base + 6][b0];
            const float2 nlo = rowmul(R0, lo, hi);   // y6=0 -> row0
            const float2 nhi = rowmul(R1, lo, hi);   // y6=1 -> row1
            lo = nlo; hi = nhi;
            bstep<32>(lo, hi, b5, b5, G1, G1);
            bstep<16>(lo, hi, b4, b4, G2, G2);
            bstep< 8>(lo, hi, b3, b3, G3, G3);
            bstep< 4>(lo, hi, b2, b2, G4, G4);
            bstep< 2>(lo, hi, b1, b1, G5, G5);
            bstep< 1>(lo, hi, b0, b0, G6, G6);
        } else {
            // ---- odd layer: folded basis pi=Gi, masks 127,63,31,15,7,3,1 ----
            const int r5 = (L >> 5) & 1;                    // y5^y6: lo=L5, hi=!L5
            const int r4 = ((L >> 4) ^ (L >> 5)) & 1;
            const int r3 = ((L >> 3) ^ (L >> 4)) & 1;
            const int r2 = ((L >> 2) ^ (L >> 3)) & 1;
            const int r1 = ((L >> 1) ^ (L >> 2)) & 1;
            const int r0 = (L ^ (L >> 1)) & 1;
            const float4 G1a = gm[base + 1][r5];
            const float4 G1b = gm[base + 1][r5 ^ 1];
            const float4 G2  = gm[base + 2][r4];
            const float4 G3  = gm[base + 3][r3];
            const float4 G4  = gm[base + 4][r2];
            const float4 G5  = gm[base + 5][r1];
            const float4 G6  = gm[base + 6][r0];
            // q0, mask 127: partner of lo[L] is hi[L^63], of hi[L] is lo[L^63]
            float2 lo63, hi63;
            lo63.x = shfx<63>(lo.x); lo63.y = shfx<63>(lo.y);
            hi63.x = shfx<63>(hi.x); hi63.y = shfx<63>(hi.y);
            const float2 nlo = rowmul(R0, lo, hi63);        // r(y)=y6=0 -> row0
            const float2 nhi = rowmul(R1, lo63, hi);        // r(y)=y6=1 -> row1
            lo = nlo; hi = nhi;
            bstep<63>(lo, hi, r5, r5 ^ 1, G1a, G1b);
            bstep<31>(lo, hi, r4, r4, G2, G2);
            bstep<15>(lo, hi, r3, r3, G3, G3);
            bstep< 7>(lo, hi, r2, r2, G4, G4);
            bstep< 3>(lo, hi, r1, r1, G5, G5);
            bstep< 1>(lo, hi, r0, r0, G6, G6);
        }
    }

    // pi_final = id -> plain planar-global f32 store (validated r12)
    const size_t TOT = (size_t)TB * DIM;
    const size_t e   = (size_t)bb * DIM + L;
    out[e]            = lo.x;
    out[e + 64]       = hi.x;
    out[TOT + e]      = lo.y;
    out[TOT + e + 64] = hi.y;
}

extern "C" void kernel_launch(void* const* d_in, const int* in_sizes, int n_in,
                              void* d_out, int out_size, void* d_ws, size_t ws_size,
                              hipStream_t stream) {
    const float* input_state;
    const float* params;
    int TB;
    if (in_sizes[0] < in_sizes[1]) {
        input_state = (const float*)d_in[0];
        params      = (const float*)d_in[1];
        TB = in_sizes[0] / DIM;
    } else {
        params      = (const float*)d_in[0];
        input_state = (const float*)d_in[1];
        TB = in_sizes[1] / DIM;
    }
    float* out = (float*)d_out;

    qsim_kernel<<<TB, 64, 0, stream>>>(input_state, params, out, TB);
}

// Round 16
// 10.653 us; speedup vs baseline: 1.0202x; 1.0202x over previous
//
#include <hip/hip_runtime.h>

#define DIM    128
#define LAYERS 8
#define NQ     7

// (E s)[x] = s[perm_g(x)] ; (E^T s)[x] = s[perm_gi(x)]  — proven on-HW (r4).
__device__ __forceinline__ int perm_g (int x) { x ^= x >> 1; x ^= x >> 2; x ^= x >> 4; return x; }
__device__ __forceinline__ int perm_gi(int x) { return x ^ (x >> 1); }

// ---- lane-permutation primitives ----
template<int CTRL>
__device__ __forceinline__ float dpp_f(float x) {
    return __int_as_float(__builtin_amdgcn_update_dpp(0, __float_as_int(x), CTRL, 0xF, 0xF, true));
}
// x[l^32]/x[l^16] via CDNA4 permlane self-swap (correctness PROVEN r15).
// Self-swap yields the two half-duplicates in some order; (a+b)-x recovers the
// partner direction-independently (err ~4e-7 << 0.068). s_nop covers the
// VALU->permlane wait-state hazard.
__device__ __forceinline__ float permxor32(float x) {
    float a = x, b = x;
    asm("s_nop 1\n\tv_permlane32_swap_b32 %0, %1" : "+v"(a), "+v"(b));
    return (a + b) - x;
}
__device__ __forceinline__ float permxor16(float x) {
    float a = x, b = x;
    asm("s_nop 1\n\tv_permlane16_swap_b32 %0, %1" : "+v"(a), "+v"(b));
    return (a + b) - x;
}

// XOR-shuffle by compile-time mask (all VALU; proven encodings r14/r15)
template<int M>
__device__ __forceinline__ float shfx(float x) {
    if constexpr      (M == 1)  return dpp_f<0xB1>(x);               // quad_perm [1,0,3,2]
    else if constexpr (M == 2)  return dpp_f<0x4E>(x);               // quad_perm [2,3,0,1]
    else if constexpr (M == 4)  return dpp_f<0x141>(dpp_f<0x1B>(x)); // l^3 then l^7 -> l^4
    else if constexpr (M == 8)  return dpp_f<0x128>(x);              // row_ror:8 == l^8
    else if constexpr (M == 16) return permxor16(x);
    else                        return permxor32(x);                 // M == 32
}

// r = m0*a + m1*b  (complex)
__device__ __forceinline__ float2 cmul2(float2 m0, float2 a, float2 m1, float2 b) {
    float2 r;
    r.x = m0.x * a.x - m0.y * a.y + m1.x * b.x - m1.y * b.y;
    r.y = m0.x * a.y + m0.y * a.x + m1.x * b.y + m1.y * b.x;
    return r;
}

template<int M>
__device__ __forceinline__ void butterfly(int L, float2& lo, float2& hi, float4 g) {
    const int bit = L & M;
    const float2 m0 = make_float2(g.x, g.y), m1 = make_float2(g.z, g.w);
    float2 plo, phl;
    plo.x = shfx<M>(lo.x); plo.y = shfx<M>(lo.y);
    phl.x = shfx<M>(hi.x); phl.y = shfx<M>(hi.y);
    const float2 a_lo = bit ? plo : lo,  b_lo = bit ? lo : plo;
    const float2 a_hi = bit ? phl : hi,  b_hi = bit ? hi : phl;
    lo = cmul2(m0, a_lo, m1, b_lo);
    hi = cmul2(m0, a_hi, m1, b_hi);
}

__global__ __launch_bounds__(64) void qsim_kernel(
        const float* __restrict__ state,          // (TB, 128) f32
        const float* __restrict__ params,         // (TB, 8, 7, 3) f32
        float* __restrict__ out,                  // f32 planar: [TB*128 re | TB*128 im]
        int TB) {
    __shared__ float4 gm[LAYERS * NQ][2];         // one wave per block

    const int L  = threadIdx.x;
    const int bb = blockIdx.x;

    // Hoist state loads: latency overlaps gate build.
    float2 lo = make_float2(state[bb * DIM + L],      0.0f);
    float2 hi = make_float2(state[bb * DIM + L + 64], 0.0f);

    // --- 56 gate matrices: lanes 0..55, native trig (|args| < ~7, err ~1e-5) ---
    if (L < LAYERS * NQ) {
        const float* pp = params + (size_t)bb * (LAYERS * NQ * 3) + L * 3;
        const float omega = pp[0], theta = pp[1], phi = pp[2];
        const float a = 0.5f * (phi + omega), b = 0.5f * (phi - omega), t = 0.5f * theta;
        const float sa = __sinf(a), ca = __cosf(a);   // e1 = (ca,-sa)
        const float sb = __sinf(b), cb = __cosf(b);   // e2 = (cb, sb)
        const float st = __sinf(t), ct = __cosf(t);
        gm[L][0] = make_float4(ca * ct, -sa * ct, -cb * st, -sb * st); // m00,m01
        gm[L][1] = make_float4(cb * st, -sb * st,  ca * ct,  sa * ct); // m10,m11
    }
    __syncthreads();   // single-wave workgroup: cheap

    const int gL = perm_g (L),  gH = perm_g (L | 64) & 63;
    const int iL = perm_gi(L),  iH = perm_gi(L | 64) & 63;

    #pragma unroll
    for (int l = 0; l < LAYERS; ++l) {
        const int base = l * NQ;
        // Register preload of this lane's gate rows (off the round-critical path).
        const float4 G0a = gm[base + 0][0];
        const float4 G0b = gm[base + 0][1];
        const float4 G1  = gm[base + 1][(L >> 5) & 1];
        const float4 G2  = gm[base + 2][(L >> 4) & 1];
        const float4 G3  = gm[base + 3][(L >> 3) & 1];
        const float4 G4  = gm[base + 4][(L >> 2) & 1];
        const float4 G5  = gm[base + 5][(L >> 1) & 1];
        const float4 G6  = gm[base + 6][L & 1];

        // q=0 (bit 6): pair lives in-lane
        {
            const float2 nlo = cmul2(make_float2(G0a.x, G0a.y), lo, make_float2(G0a.z, G0a.w), hi);
            const float2 nhi = cmul2(make_float2(G0b.x, G0b.y), lo, make_float2(G0b.z, G0b.w), hi);
            lo = nlo; hi = nhi;
        }
        butterfly<32>(L, lo, hi, G1);   // VALU (permlane32)
        butterfly<16>(L, lo, hi, G2);   // VALU (permlane16)
        butterfly< 8>(L, lo, hi, G3);   // DPP
        butterfly< 4>(L, lo, hi, G4);   // DPP x2
        butterfly< 2>(L, lo, hi, G5);   // DPP
        butterfly< 1>(L, lo, hi, G6);   // DPP

        // entangler: E (even l) / E^T (odd l) — the ONLY LDS op per layer
        const int sl = (l & 1) ? iL : gL;
        const int sh = (l & 1) ? iH : gH;
        float2 nlo, nhi;
        nlo.x = __shfl(lo.x, sl); nlo.y = __shfl(lo.y, sl);
        nhi.x = __shfl(hi.x, sh); nhi.y = __shfl(hi.y, sh);
        lo = nlo; hi = nhi;
    }

    // --- planar-global f32 store (validated r12): [all re | all im] ---
    const size_t TOT = (size_t)TB * DIM;
    const size_t e   = (size_t)bb * DIM + L;
    out[e]            = lo.x;
    out[e + 64]       = hi.x;
    out[TOT + e]      = lo.y;
    out[TOT + e + 64] = hi.y;
}

extern "C" void kernel_launch(void* const* d_in, const int* in_sizes, int n_in,
                              void* d_out, int out_size, void* d_ws, size_t ws_size,
                              hipStream_t stream) {
    // d_in[0]=state (TB*128), d_in[1]=params (TB*168); size-disambiguated safety net.
    const float* input_state;
    const float* params;
    int TB;
    if (in_sizes[0] < in_sizes[1]) {
        input_state = (const float*)d_in[0];
        params      = (const float*)d_in[1];
        TB = in_sizes[0] / DIM;
    } else {
        params      = (const float*)d_in[0];
        input_state = (const float*)d_in[1];
        TB = in_sizes[1] / DIM;
    }
    float* out = (float*)d_out;   // f32 buffer (proven r10/r11)

    qsim_kernel<<<TB, 64, 0, stream>>>(input_state, params, out, TB);
}